// Round 3
// baseline (809.253 us; speedup 1.0000x reference)
//
#include <hip/hip_runtime.h>

#define BB 4
#define SS 2048
#define DD 2048
#define HH 16
#define DHD 128
#define MAXL 1024

typedef __bf16 bf16x8 __attribute__((ext_vector_type(8)));
typedef float f32x4 __attribute__((ext_vector_type(4)));
typedef unsigned int u32_as1 __attribute__((address_space(1)));
typedef unsigned int u32_as3 __attribute__((address_space(3)));

__device__ __forceinline__ unsigned short f2bf(float f) {
  unsigned int u = __builtin_bit_cast(unsigned int, f);
  u += 0x7fffu + ((u >> 16) & 1u);   // RNE
  return (unsigned short)(u >> 16);
}
__device__ __forceinline__ float bf2f(unsigned short h) {
  unsigned int u = ((unsigned int)h) << 16;
  return __builtin_bit_cast(float, u);
}
union U4 { uint4 u; bf16x8 b; };
__device__ __forceinline__ bf16x8 ldfrag(const unsigned short* p) {
  U4 x; x.u = *(const uint4*)p; return x.b;
}
__device__ __forceinline__ void gl_lds16(const void* g, void* l) {
  __builtin_amdgcn_global_load_lds((const u32_as1*)g, (u32_as3*)l, 16, 0, 0);
}

// DPP 16-lane butterfly reduction (VALU pipe).
template <int C>
__device__ __forceinline__ float dppf(float x) {
  return __builtin_bit_cast(float,
      __builtin_amdgcn_mov_dpp(__builtin_bit_cast(int, x), C, 0xF, 0xF, true));
}
__device__ __forceinline__ float rmax16(float x) {
  x = fmaxf(x, dppf<0xB1>(x));
  x = fmaxf(x, dppf<0x4E>(x));
  x = fmaxf(x, dppf<0x141>(x));
  x = fmaxf(x, dppf<0x140>(x));
  return x;
}
__device__ __forceinline__ float radd16(float x) {
  x += dppf<0xB1>(x);
  x += dppf<0x4E>(x);
  x += dppf<0x141>(x);
  x += dppf<0x140>(x);
  return x;
}

// ---------------------------------------------------------------------------
__global__ void build_pos(const int* __restrict__ skip, int* __restrict__ posk,
                          int* __restrict__ nval) {
  int b = blockIdx.x, t = threadIdx.x;  // 64 threads
  __shared__ int cnts[64], offs[64];
  const int* row = skip + b * SS;
  int c = 0;
  for (int i = 0; i < 32; i++) c += (row[t * 32 + i] != 0);
  cnts[t] = c;
  __syncthreads();
  if (t == 0) {
    int run = 0;
    for (int i = 0; i < 64; i++) { offs[i] = run; run += cnts[i]; }
    nval[b] = run > MAXL ? MAXL : run;
  }
  __syncthreads();
  int o = offs[t];
  for (int i = 0; i < 32; i++)
    if (row[t * 32 + i]) { if (o < MAXL) posk[b * MAXL + o] = t * 32 + i; o++; }
  int nb = nval[b];
  for (int l = nb + t; l < MAXL; l += 64) posk[b * MAXL + l] = -1;
}

// ---------------------------------------------------------------------------
__global__ __launch_bounds__(256) void cvt3(const float* __restrict__ q,
                                            const float* __restrict__ k,
                                            const float* __restrict__ v,
                                            unsigned short* __restrict__ oq,
                                            unsigned short* __restrict__ ok,
                                            unsigned short* __restrict__ ov) {
  const int nq = BB * MAXL * DD / 4, nk = BB * SS * DD / 4;
  int idx = blockIdx.x * 256 + threadIdx.x;
  const float* src; unsigned short* dst; int off;
  if (idx < nq) { src = q; dst = oq; off = idx; }
  else if (idx < nq + nk) { src = k; dst = ok; off = idx - nq; }
  else { src = v; dst = ov; off = idx - nq - nk; }
  float4 vv = ((const float4*)src)[off];
  ushort4 h;
  h.x = f2bf(vv.x); h.y = f2bf(vv.y); h.z = f2bf(vv.z); h.w = f2bf(vv.w);
  ((ushort4*)dst)[off] = h;
}

// ---------------------------------------------------------------------------
__global__ __launch_bounds__(256) void transpose_w4(const float* __restrict__ w0,
    const float* __restrict__ w1, const float* __restrict__ w2, const float* __restrict__ w3,
    unsigned short* __restrict__ o0, unsigned short* __restrict__ o1,
    unsigned short* __restrict__ o2, unsigned short* __restrict__ o3) {
  __shared__ __align__(16) unsigned short tile[64 * 76];
  const float* W; unsigned short* Wt;
  switch (blockIdx.z) {
    case 0: W = w0; Wt = o0; break;
    case 1: W = w1; Wt = o1; break;
    case 2: W = w2; Wt = o2; break;
    default: W = w3; Wt = o3; break;
  }
  int tx = threadIdx.x;
  int K0 = blockIdx.y * 64, N0 = blockIdx.x * 64;
  #pragma unroll
  for (int i = 0; i < 4; i++) {
    int r = (tx >> 4) + i * 16, c4 = (tx & 15) * 4;
    float4 v = *(const float4*)&W[(size_t)(K0 + r) * DD + N0 + c4];
    ushort4 h;
    h.x = f2bf(v.x); h.y = f2bf(v.y); h.z = f2bf(v.z); h.w = f2bf(v.w);
    *(ushort4*)&tile[r * 76 + c4] = h;
  }
  __syncthreads();
  #pragma unroll
  for (int i = 0; i < 4; i++) {
    int n = (tx >> 4) + i * 16, k4 = (tx & 15) * 4;
    ushort4 h;
    h.x = tile[(k4 + 0) * 76 + n];
    h.y = tile[(k4 + 1) * 76 + n];
    h.z = tile[(k4 + 2) * 76 + n];
    h.w = tile[(k4 + 3) * 76 + n];
    *(ushort4*)&Wt[(size_t)(N0 + n) * DD + K0 + k4] = h;
  }
}

// ---------------------------------------------------------------------------
// BMx256-tile bf16 GEMM, BK=64, 512 threads (8 waves, 2M x 4N).
// FRAGMENT-ORDERED LDS: each 1KB MFMA fragment (16 rows x 4 chunks of 16B) is
// staged contiguously ([frag][lane][16B]) by giving global_load_lds per-lane
// source addresses in fragment order. Every ds_read_b128 is then base+lane*16
// -> stride-1, zero bank conflicts (the old row-major+XOR layout was 8-way
// aliased: 128B rows put every chunk column on the same 4 banks).
// Double-buffered, counted s_waitcnt vmcnt(N) (never 0 mid-loop), raw
// s_barrier phases, s_setprio around MFMA clusters.
// mode 0: head-split bf16 [b][h][l][128]; mode 1: fp32 [M][N]; mode 2: V^T.
template <int BM>
__global__ __launch_bounds__(512, 2) void gemm8(const unsigned short* __restrict__ A,
                                                const unsigned short* __restrict__ Bt,
                                                void* __restrict__ Cp,
                                                int M, int N, int K, int mode, int Lbits) {
  constexpr int AFR = BM / 8;                        // A frags per buffer (32/16)
  __shared__ __align__(16) unsigned short lds[(AFR + 32) * 1024];
  unsigned short* const Abuf = lds;                  // [2][AFR*512]
  unsigned short* const Bbuf = lds + 2 * AFR * 512;  // [2][32*512]

  const int tid = threadIdx.x;
  const int lane = tid & 63, quad = lane >> 4, c = lane & 15;
  const int w = tid >> 6;
  const int wm = (w >> 2) * (BM / 2), wn = (w & 3) * 64;

  // XCD-aware block swizzle (nwg multiple of 8 for all launches)
  const int nwg = gridDim.x * gridDim.y;
  const int bid0 = blockIdx.y * gridDim.x + blockIdx.x;
  const int cpx = nwg >> 3;
  const int bid = (bid0 & 7) * cpx + (bid0 >> 3);
  const int bx = bid % gridDim.x;
  const int by = bid / gridDim.x;
  const size_t tm = (size_t)by * BM, tn = (size_t)bx * 256;

  constexpr int MR = BM / 32;
  f32x4 acc[MR][4] = {};

  // frag f covers rows (f>>1)*16+c, chunk (f&1)*4+quad. Wave w stages frags
  // f = n*8+w; LDS dest = frag base + lane*16B (linear).
  constexpr int AN = AFR / 8;        // A issues per thread (4 or 2)
  constexpr int NLD = AN + 4;
  const unsigned short* gA = A + (tm + c) * (size_t)K + quad * 8;
  const unsigned short* gB = Bt + (tn + c) * (size_t)K + quad * 8;

  auto STAGE = [&](int sel, int kk) {
    unsigned short* ad = Abuf + sel * (AFR * 512) + lane * 8;
    unsigned short* bd = Bbuf + sel * 16384 + lane * 8;
    #pragma unroll
    for (int n = 0; n < AN; n++) {
      int f = n * 8 + w;
      gl_lds16(gA + kk + ((size_t)(f >> 1) * 16) * K + (f & 1) * 32, ad + f * 512);
    }
    #pragma unroll
    for (int n = 0; n < 4; n++) {
      int f = n * 8 + w;
      gl_lds16(gB + kk + ((size_t)(f >> 1) * 16) * K + (f & 1) * 32, bd + f * 512);
    }
  };

  const int nkt = K >> 6;
  STAGE(0, 0);

  const int ai0 = (wm >> 4) * 2;     // A frag id base (i_global*2)
  const int bj0 = (wn >> 4) * 2;     // B frag id base

  for (int t = 0; t < nkt; ++t) {
    const int sel = t & 1;
    const unsigned short* as = Abuf + sel * (AFR * 512) + lane * 8;
    const unsigned short* bs = Bbuf + sel * 16384 + lane * 8;
    if (t + 1 < nkt) {
      STAGE(sel ^ 1, (t + 1) << 6);
      asm volatile("s_waitcnt vmcnt(%0)" ::"i"(NLD) : "memory");  // tile t landed
    } else {
      asm volatile("s_waitcnt vmcnt(0)" ::: "memory");
    }
    __builtin_amdgcn_s_barrier();

    bf16x8 a0[4][2], b01[2][2], b23[2][2];
    // ---- P1: ds_read A m-half0 + B j01; MFMA (m0 x j01)
    #pragma unroll
    for (int i = 0; i < 4; i++)
      #pragma unroll
      for (int ks = 0; ks < 2; ks++)
        a0[i][ks] = ldfrag(&as[(ai0 + i * 2 + ks) * 512]);
    #pragma unroll
    for (int j = 0; j < 2; j++)
      #pragma unroll
      for (int ks = 0; ks < 2; ks++)
        b01[j][ks] = ldfrag(&bs[(bj0 + j * 2 + ks) * 512]);
    __builtin_amdgcn_s_barrier();
    __builtin_amdgcn_s_setprio(1);
    #pragma unroll
    for (int i = 0; i < 4; i++)
      #pragma unroll
      for (int j = 0; j < 2; j++)
        #pragma unroll
        for (int ks = 0; ks < 2; ks++)
          acc[i][j] = __builtin_amdgcn_mfma_f32_16x16x32_bf16(a0[i][ks], b01[j][ks], acc[i][j], 0, 0, 0);
    __builtin_amdgcn_s_setprio(0);
    __builtin_amdgcn_s_barrier();
    // ---- P2: ds_read B j23; MFMA (m0 x j23)
    #pragma unroll
    for (int j = 0; j < 2; j++)
      #pragma unroll
      for (int ks = 0; ks < 2; ks++)
        b23[j][ks] = ldfrag(&bs[(bj0 + (2 + j) * 2 + ks) * 512]);
    __builtin_amdgcn_s_barrier();
    __builtin_amdgcn_s_setprio(1);
    #pragma unroll
    for (int i = 0; i < 4; i++)
      #pragma unroll
      for (int j = 0; j < 2; j++)
        #pragma unroll
        for (int ks = 0; ks < 2; ks++)
          acc[i][2 + j] = __builtin_amdgcn_mfma_f32_16x16x32_bf16(a0[i][ks], b23[j][ks], acc[i][2 + j], 0, 0, 0);
    __builtin_amdgcn_s_setprio(0);
    __builtin_amdgcn_s_barrier();

    if constexpr (BM == 256) {
      // ---- P3: ds_read A m-half1; MFMA (m1 x j01)
      bf16x8 a1[4][2];
      #pragma unroll
      for (int i = 0; i < 4; i++)
        #pragma unroll
        for (int ks = 0; ks < 2; ks++)
          a1[i][ks] = ldfrag(&as[(ai0 + (4 + i) * 2 + ks) * 512]);
      __builtin_amdgcn_s_barrier();
      __builtin_amdgcn_s_setprio(1);
      #pragma unroll
      for (int i = 0; i < 4; i++)
        #pragma unroll
        for (int j = 0; j < 2; j++)
          #pragma unroll
          for (int ks = 0; ks < 2; ks++)
            acc[4 + i][j] = __builtin_amdgcn_mfma_f32_16x16x32_bf16(a1[i][ks], b01[j][ks], acc[4 + i][j], 0, 0, 0);
      __builtin_amdgcn_s_setprio(0);
      __builtin_amdgcn_s_barrier();
      // ---- P4: MFMA (m1 x j23)
      __builtin_amdgcn_s_setprio(1);
      #pragma unroll
      for (int i = 0; i < 4; i++)
        #pragma unroll
        for (int j = 0; j < 2; j++)
          #pragma unroll
          for (int ks = 0; ks < 2; ks++)
            acc[4 + i][2 + j] = __builtin_amdgcn_mfma_f32_16x16x32_bf16(a1[i][ks], b23[j][ks], acc[4 + i][2 + j], 0, 0, 0);
      __builtin_amdgcn_s_setprio(0);
      __builtin_amdgcn_s_barrier();
    }
  }

  // ---- epilogue: staging LDS dead; per-wave 64x68 bounce regions
  if (mode == 1) {
    float* Cf = (float*)Cp;
    #pragma unroll
    for (int i = 0; i < MR; i++)
      #pragma unroll
      for (int j = 0; j < 4; j++)
        #pragma unroll
        for (int r = 0; r < 4; r++) {
          size_t m = tm + wm + i * 16 + quad * 4 + r;
          size_t n = tn + wn + j * 16 + c;
          Cf[m * N + n] = acc[i][j][r];
        }
    return;
  }
  unsigned short* Cb = (unsigned short*)Cp;
  unsigned short* ep = lds + w * 4352;   // per-wave [64][68] bounce tile
  constexpr int MH = BM / 128;
  if (mode == 0) {
    const size_t Lmask = ((size_t)1 << Lbits) - 1;
    #pragma unroll
    for (int mh = 0; mh < MH; mh++) {
      #pragma unroll
      for (int i = 0; i < 4; i++)
        #pragma unroll
        for (int j = 0; j < 4; j++)
          #pragma unroll
          for (int r = 0; r < 4; r++)
            ep[(i * 16 + quad * 4 + r) * 68 + j * 16 + c] = f2bf(acc[mh * 4 + i][j][r]);
      #pragma unroll
      for (int it = 0; it < 8; it++) {
        int chunk = it * 64 + lane;
        int ml = chunk >> 3, nc = (chunk & 7) * 8;
        uint4 val = *(const uint4*)&ep[ml * 68 + nc];
        size_t m = tm + wm + mh * 64 + ml, n = tn + wn + nc;
        size_t b = m >> Lbits, l = m & Lmask, h = n >> 7, d = n & 127;
        *(uint4*)&Cb[(((b * HH + h) << Lbits) + l) * 128 + d] = val;
      }
    }
  } else {
    // mode 2: stage transposed [n][m], write V^T [b][h][d][S]
    #pragma unroll
    for (int mh = 0; mh < MH; mh++) {
      #pragma unroll
      for (int i = 0; i < 4; i++)
        #pragma unroll
        for (int j = 0; j < 4; j++)
          #pragma unroll
          for (int r = 0; r < 4; r++)
            ep[(j * 16 + c) * 68 + i * 16 + quad * 4 + r] = f2bf(acc[mh * 4 + i][j][r]);
      #pragma unroll
      for (int it = 0; it < 8; it++) {
        int chunk = it * 64 + lane;
        int nl = chunk >> 3, mc = (chunk & 7) * 8;
        uint4 val = *(const uint4*)&ep[nl * 68 + mc];
        size_t n = tn + wn + nl, m = tm + wm + mh * 64 + mc;
        size_t b = m >> 11, s = m & 2047, h = n >> 7, d = n & 127;
        *(uint4*)&Cb[((b * HH + h) * 128 + d) * SS + s] = val;
      }
    }
  }
}

// ---------------------------------------------------------------------------
// fused RoPE. Q additionally pre-scaled by 1/sqrt(128)*log2(e) so attention
// softmax runs in base-2 with no per-element scale (exp2 only).
__global__ __launch_bounds__(256) void rope2(unsigned short* __restrict__ xq,
                                             unsigned short* __restrict__ xk,
                                             const int* __restrict__ posk) {
  constexpr float QSCL = (float)(0.08838834764831843 * 1.4426950408889634);
  const int Nq = BB * HH * MAXL * 64;
  int gid = blockIdx.x * 256 + threadIdx.x;
  unsigned short* x; int Lbits, idx, use_posk;
  if (gid < Nq) { x = xq; Lbits = 10; use_posk = 1; idx = gid; }
  else { x = xk; Lbits = 11; use_posk = 0; idx = gid - Nq; }
  int d = idx & 63;
  int rest = idx >> 6;
  int l = rest & ((1 << Lbits) - 1);
  int bh = rest >> Lbits;
  int b = bh >> 4;
  int p = use_posk ? posk[(b << 10) + l] : l;
  float ang = (float)p * __expf(-(float)d * 0.14391156831212787f); // ln(1e4)/64
  float sn, cs;
  __sincosf(ang, &sn, &cs);
  float S = use_posk ? QSCL : 1.0f;
  size_t base = (size_t)rest * 128;
  float x1 = bf2f(x[base + d]), x2 = bf2f(x[base + d + 64]);
  x[base + d]      = f2bf((x1 * cs - x2 * sn) * S);
  x[base + d + 64] = f2bf((x2 * cs + x1 * sn) * S);
}

// ---------------------------------------------------------------------------
// Flash attention. FRAGMENT-ORDERED LDS (stride-1 conflict-free ds_read_b128
// for K, V^T and the P bounce). Single-buffered K and V with a 4-barrier
// schedule and exact counted vmcnt: K[t+1] staged after QK^T reads retire,
// V[t+1] staged after PV reads retire; waits never drain mid-loop.
// LDS = 16K (K) + 16K (V^T) + 8K (P) = 40KB -> 4 blocks/CU (16 waves).
// Softmax in base-2 (Q pre-scaled in rope2); wave-uniform mask skip on fully
// visible tiles; per-wave causal early-out.
__global__ __launch_bounds__(256, 4) void attn_kernel(const unsigned short* __restrict__ qp,
                                                      const unsigned short* __restrict__ kp,
                                                      const unsigned short* __restrict__ vtp,
                                                      const int* __restrict__ posk,
                                                      const int* __restrict__ nval,
                                                      unsigned short* __restrict__ ctx) {
  __shared__ __align__(16) unsigned short k_s[8192];   // 16 frags x 1KB
  __shared__ __align__(16) unsigned short vt_s[8192];  // 16 frags x 1KB
  __shared__ __align__(16) unsigned short p_s[4096];   // 4 waves x 2 frags

  const int tid = threadIdx.x;
  const int w = tid >> 6, lane = tid & 63, quad = lane >> 4, c = lane & 15;
  const int bh = blockIdx.x, b = bh >> 4, h = bh & 15;
  const int qbase = blockIdx.y * 64;
  const int nb = nval[b];
  const int* pb = posk + (b << 10) + qbase;

  int lv = nb - 1 - qbase; lv = lv > 63 ? 63 : lv;
  const int nkt = (lv >= 0) ? ((pb[lv] >> 6) + 1) : 0;
  const bool whas = (w * 16 <= lv);
  int wl = w * 16 + 15; if (wl > lv) wl = lv;
  const int wkmax = whas ? pb[wl] : -1;
  const int kminw = whas ? pb[w * 16] : -1;

  int km[4];
  #pragma unroll
  for (int r = 0; r < 4; r++) km[r] = pb[w * 16 + quad * 4 + r];

  // Q fragments in registers (A-layout: m=c, k = ks*32+quad*8+e)
  const unsigned short* qg = qp + (((size_t)bh << 10) + qbase) * 128;
  bf16x8 aq[4];
  #pragma unroll
  for (int ks = 0; ks < 4; ks++)
    aq[ks] = ldfrag(&qg[(size_t)(w * 16 + c) * 128 + ks * 32 + quad * 8]);

  // staging (frag-ordered): wave w stages frags f = n*4+w, n=0..3.
  // K frag f: key row (f>>2)*16+c, d-chunk (f&3)*4+quad.
  const unsigned short* kgp = kp + ((size_t)bh * SS + c) * 128 + (w * 4 + quad) * 8;
  auto STG_K = [&](int kb) {
    #pragma unroll
    for (int n = 0; n < 4; n++)
      gl_lds16(kgp + (size_t)(kb + n * 16) * 128, &k_s[(n * 4 + w) * 512 + lane * 8]);
  };
  // V frag f: d row (f>>1)*16+c, s-chunk (f&1)*4+quad.
  auto STG_V = [&](int kb) {
    #pragma unroll
    for (int n = 0; n < 4; n++) {
      int f = n * 4 + w;
      gl_lds16(vtp + ((size_t)bh * 128 + (f >> 1) * 16 + c) * SS + kb + ((f & 1) * 4 + quad) * 8,
               &vt_s[f * 512 + lane * 8]);
    }
  };

  float m_i[4], l_i[4];
  #pragma unroll
  for (int r = 0; r < 4; r++) { m_i[r] = -1e30f; l_i[r] = 0.f; }
  f32x4 o[8];
  #pragma unroll
  for (int dj = 0; dj < 8; dj++) o[dj] = (f32x4){0.f, 0.f, 0.f, 0.f};

  // P bounce (frag-ordered): write base for this thread
  const int pwb = w * 1024 + quad * 32 + (c & 7) + (c >> 3) * 128;

  if (nkt > 0) { STG_K(0); STG_V(0); }

  for (int kt = 0; kt < nkt; kt++) {
    const int kb = kt * 64;
    const bool more = (kt + 1 < nkt);
    // K[kt] landed (8 newest = V[kt] or next-tile loads may stay in flight)
    asm volatile("s_waitcnt vmcnt(8)" ::: "memory");
    __builtin_amdgcn_s_barrier();

    const bool act = (kb <= wkmax);
    f32x4 sa[4];
    if (act) {
      #pragma unroll
      for (int j = 0; j < 4; j++) {
        sa[j] = (f32x4){0.f, 0.f, 0.f, 0.f};
        #pragma unroll
        for (int ks = 0; ks < 4; ks++) {
          bf16x8 bk = ldfrag(&k_s[(j * 4 + ks) * 512 + lane * 8]);
          sa[j] = __builtin_amdgcn_mfma_f32_16x16x32_bf16(aq[ks], bk, sa[j], 0, 0, 0);
        }
      }
    }
    __builtin_amdgcn_s_barrier();        // all k_s reads retired
    if (more) STG_K(kb + 64);

    if (act) {
      // online softmax, base-2 (Q pre-scaled by 1/sqrt(DH)*log2e)
      float mt[4] = {-1e30f, -1e30f, -1e30f, -1e30f};
      if (kb + 63 <= kminw) {            // fully visible: no masking needed
        #pragma unroll
        for (int j = 0; j < 4; j++)
          #pragma unroll
          for (int r = 0; r < 4; r++) mt[r] = fmaxf(mt[r], sa[j][r]);
      } else {
        #pragma unroll
        for (int j = 0; j < 4; j++) {
          int key = kb + j * 16 + c;
          #pragma unroll
          for (int r = 0; r < 4; r++) {
            float v = (key <= km[r]) ? sa[j][r] : -1e30f;
            sa[j][r] = v;
            mt[r] = fmaxf(mt[r], v);
          }
        }
      }
      float al[4], rs[4];
      #pragma unroll
      for (int r = 0; r < 4; r++) {
        mt[r] = rmax16(mt[r]);
        float mn = fmaxf(m_i[r], mt[r]);
        al[r] = __builtin_exp2f(m_i[r] - mn);
        m_i[r] = mn;
        rs[r] = 0.f;
      }
      #pragma unroll
      for (int j = 0; j < 4; j++)
        #pragma unroll
        for (int r = 0; r < 4; r++) {
          float pv = __builtin_exp2f(sa[j][r] - m_i[r]);
          sa[j][r] = pv;
          rs[r] += pv;
        }
      #pragma unroll
      for (int r = 0; r < 4; r++) {
        rs[r] = radd16(rs[r]);
        l_i[r] = l_i[r] * al[r] + rs[r];
      }
      #pragma unroll
      for (int dj = 0; dj < 8; dj++)
        #pragma unroll
        for (int r = 0; r < 4; r++) o[dj][r] *= al[r];
    }

    if (more) { asm volatile("s_waitcnt vmcnt(8)" ::: "memory"); }  // V[kt] landed
    else      { asm volatile("s_waitcnt vmcnt(0)" ::: "memory"); }
    __builtin_amdgcn_s_barrier();

    if (act) {
      // P: C-layout -> frag-ordered LDS -> A-layout (per-wave region)
      #pragma unroll
      for (int j = 0; j < 4; j++)
        #pragma unroll
        for (int r = 0; r < 4; r++)
          p_s[pwb + (j >> 1) * 512 + (j & 1) * 256 + r * 8] = f2bf(sa[j][r]);
      #pragma unroll
      for (int ks2 = 0; ks2 < 2; ks2++) {
        bf16x8 ap = ldfrag(&p_s[(w * 2 + ks2) * 512 + lane * 8]);
        #pragma unroll
        for (int dj = 0; dj < 8; dj++) {
          bf16x8 bv = ldfrag(&vt_s[(dj * 2 + ks2) * 512 + lane * 8]);
          o[dj] = __builtin_amdgcn_mfma_f32_16x16x32_bf16(ap, bv, o[dj], 0, 0, 0);
        }
      }
    }
    __builtin_amdgcn_s_barrier();        // all vt_s reads retired
    if (more) STG_V(kb + 64);
  }

  #pragma unroll
  for (int r = 0; r < 4; r++) {
    int l = qbase + w * 16 + quad * 4 + r;
    bool ok = (l < nb);
    float inv = ok ? (1.0f / l_i[r]) : 0.0f;
    #pragma unroll
    for (int dj = 0; dj < 8; dj++)
      ctx[(((size_t)b << 10) + l) * (size_t)DD + h * 128 + dj * 16 + c] =
          f2bf(ok ? o[dj][r] * inv : 0.0f);
  }
}

// ---------------------------------------------------------------------------
extern "C" void kernel_launch(void* const* d_in, const int* in_sizes, int n_in,
                              void* d_out, int out_size, void* d_ws, size_t ws_size,
                              hipStream_t stream) {
  const float* q_src = (const float*)d_in[0];
  const float* k_src = (const float*)d_in[1];
  const float* v_src = (const float*)d_in[2];
  const float* Wq = (const float*)d_in[3];
  const float* Wk = (const float*)d_in[4];
  const float* Wv = (const float*)d_in[5];
  const float* Wo = (const float*)d_in[6];
  const int* skip = (const int*)d_in[9];

  char* p = (char*)d_ws;
  auto alloc = [&](size_t bytes) -> char* {
    char* r = p;
    p += (bytes + 255) & ~(size_t)255;
    return r;
  };
  unsigned short* a_q  = (unsigned short*)alloc((size_t)BB * MAXL * DD * 2);
  unsigned short* a_k  = (unsigned short*)alloc((size_t)BB * SS * DD * 2);
  unsigned short* a_v  = (unsigned short*)alloc((size_t)BB * SS * DD * 2);
  unsigned short* wt_q = (unsigned short*)alloc((size_t)DD * DD * 2);
  unsigned short* wt_k = (unsigned short*)alloc((size_t)DD * DD * 2);
  unsigned short* wt_v = (unsigned short*)alloc((size_t)DD * DD * 2);
  unsigned short* wt_o = (unsigned short*)alloc((size_t)DD * DD * 2);
  unsigned short* q_pro = (unsigned short*)alloc((size_t)BB * HH * MAXL * DHD * 2);
  unsigned short* k_pro = (unsigned short*)alloc((size_t)BB * HH * SS * DHD * 2);
  unsigned short* v_t   = (unsigned short*)alloc((size_t)BB * HH * SS * DHD * 2);
  int* posk = (int*)alloc((size_t)BB * MAXL * 4);
  int* nval = (int*)alloc(64);
  unsigned short* ctx = a_q;  // a_q dead after Q projection

  build_pos<<<BB, 64, 0, stream>>>(skip, posk, nval);
  cvt3<<<(BB * MAXL * DD + 2 * BB * SS * DD) / (4 * 256), 256, 0, stream>>>(
      q_src, k_src, v_src, a_q, a_k, a_v);
  transpose_w4<<<dim3(32, 32, 4), 256, 0, stream>>>(Wq, Wk, Wv, Wo, wt_q, wt_k, wt_v, wt_o);

  gemm8<128><<<dim3(8, 32), 512, 0, stream>>>(a_q, wt_q, q_pro, BB * MAXL, DD, DD, 0, 10);
  gemm8<256><<<dim3(8, 32), 512, 0, stream>>>(a_k, wt_k, k_pro, BB * SS, DD, DD, 0, 11);
  gemm8<256><<<dim3(8, 32), 512, 0, stream>>>(a_v, wt_v, v_t, BB * SS, DD, DD, 2, 11);

  rope2<<<(BB * HH * (MAXL + SS) * 64) / 256, 256, 0, stream>>>(q_pro, k_pro, posk);

  attn_kernel<<<dim3(BB * HH, MAXL / 64), 256, 0, stream>>>(q_pro, k_pro, v_t, posk, nval, ctx);

  gemm8<128><<<dim3(8, 32), 512, 0, stream>>>(ctx, wt_o, d_out, BB * MAXL, DD, DD, 1, 0);
}